// Round 5
// baseline (7627.736 us; speedup 1.0000x reference)
//
#include <hip/hip_runtime.h>
#include <math.h>

#define HID 512
#define SEQ 512
#define EMB 345
#define NN  513
#define MPAD 576
#define H4  2048
#define H2  1024

// ---------------------------------------------------------------- GEMM (NT)
// C[m][n] = sum_k A[m][k]*B[n][k] (+ bias[n]); BM=BN=64, TK=16, 256 thr, 4x4
__global__ __launch_bounds__(256)
void gemm_nt(const float* __restrict__ A, int lda, long aStride,
             const float* __restrict__ B, int ldb, long bStride,
             const float* __restrict__ bias, long biasStride,
             float* __restrict__ C, int ldc, long cStride, int K)
{
    int z = blockIdx.z;
    A += (long)z * aStride; B += (long)z * bStride; C += (long)z * cStride;
    const float* bptr = bias ? bias + (long)z * biasStride : nullptr;
    __shared__ float As[16][68];
    __shared__ float Bs[16][68];
    int tid = threadIdx.x;
    int tx = tid & 15, ty = tid >> 4;
    int m0 = blockIdx.y * 64, n0 = blockIdx.x * 64;
    float acc[4][4] = {};
    for (int k0 = 0; k0 < K; k0 += 16) {
        #pragma unroll
        for (int i = 0; i < 4; i++) {
            int id = tid + 256 * i;
            int mn = id >> 4, kk = id & 15;
            int k = k0 + kk;
            As[kk][mn] = (k < K) ? A[(long)(m0 + mn) * lda + k] : 0.f;
            Bs[kk][mn] = (k < K) ? B[(long)(n0 + mn) * ldb + k] : 0.f;
        }
        __syncthreads();
        #pragma unroll
        for (int kk = 0; kk < 16; kk++) {
            float a[4], b[4];
            #pragma unroll
            for (int i = 0; i < 4; i++) a[i] = As[kk][ty * 4 + i];
            #pragma unroll
            for (int j = 0; j < 4; j++) b[j] = Bs[kk][tx * 4 + j];
            #pragma unroll
            for (int i = 0; i < 4; i++)
                #pragma unroll
                for (int j = 0; j < 4; j++) acc[i][j] += a[i] * b[j];
        }
        __syncthreads();
    }
    #pragma unroll
    for (int i = 0; i < 4; i++) {
        int m = m0 + ty * 4 + i;
        #pragma unroll
        for (int j = 0; j < 4; j++) {
            int n = n0 + tx * 4 + j;
            float v = acc[i][j];
            if (bptr) v += bptr[n];
            C[(long)m * ldc + n] = v;
        }
    }
}

// ---------------------------------------------------------------- LSTM layer
// fast activations: v_exp_f32 + v_rcp_f32 (~1e-6 rel err; tolerance is 0.39)
__device__ __forceinline__ float sigmf(float x)
{ return __builtin_amdgcn_rcpf(1.f + __expf(-x)); }
__device__ __forceinline__ float tanhf_fast(float x)
{ return 1.f - 2.f * __builtin_amdgcn_rcpf(1.f + __expf(2.f * x)); }
// x=+inf: exp=inf, rcp=0 -> 1; x=-inf: exp=0 -> -1. No NaN.

__device__ __forceinline__ bool badw(unsigned long long a)
{ return ((unsigned)a == 0xFFFFFFFFu) || ((unsigned)(a >> 32) == 0xFFFFFFFFu); }

// 64 WGs: wg>>5 = dir, (wg&31)*16 = cell base (16 cells/WG, 4/wave).
// WAVE-AUTONOMOUS: zero barriers in the step loop. Lane = g*16 + ci*4 + kp
// (gate, cell-in-wave, k-quarter). Each lane holds 128 Whh weights pinned
// into VGPRs via asm (compiler at VGPR=100 was silently re-loading from L2
// every step — R4 post-mortem). Each wave polls the FULL previous-h vector
// (8 floats/lane, data-as-flag sentinel 0xFF), stages it in a wave-private
// LDS region (chunk stride 132 -> conflict-free b128 reads), MACs, reduces
// k via 2 shfl_xor, gathers gates via 3 shfl, activates on 4 lanes, stores.
__global__ __launch_bounds__(256, 1)
void lstm_layer(const float* __restrict__ zin,   // [2][SEQ][H4]
                const float* __restrict__ Whh,   // [2][H4][HID]
                float* out)                      // [SEQ][H2], pre-memset 0xFF
{
    int wg  = blockIdx.x;
    int dir = wg >> 5;
    int kb  = (wg & 31) * 16;
    int tid = threadIdx.x;
    int p   = tid >> 6;          // wave id: cells 4p..4p+3
    int l   = tid & 63;
    int g   = l >> 4;            // gate (torch order i,f,g,o)
    int ci  = (l >> 2) & 3;      // cell within wave
    int kp  = l & 3;             // k quarter
    int cell = kb + 4 * p + ci;  // cell index within direction
    long row = (long)g * 512 + cell;

    __shared__ float hshare[4][4 * 132];   // wave-private staging, 8.4 KB

    float wreg[128];
    {
        const float4* wp = (const float4*)(Whh + ((long)dir * H4 + row) * HID + kp * 128);
        #pragma unroll
        for (int j = 0; j < 32; j++) {
            float4 w = wp[j];
            wreg[4*j+0] = w.x; wreg[4*j+1] = w.y; wreg[4*j+2] = w.z; wreg[4*j+3] = w.w;
        }
    }
    // pin: values now "come from" the asm; cannot be rematerialized from memory
    #pragma unroll
    for (int j = 0; j < 128; j++) asm volatile("" : "+v"(wreg[j]));

    const float* zin_d = zin + (long)dir * SEQ * H4;
    float* myLds = hshare[p];
    float c_st = 0.f;
    bool actlane = (l < 16) && ((l & 3) == 0);   // g==0 && kp==0; ci = l>>2

    for (int t = 0; t < SEQ; t++) {
        int at = (dir == 0) ? t : (SEQ - 1 - t);
        // zin prefetch on kp==0 lanes (1 float each), issued before the poll
        float zv = 0.f;
        if (kp == 0) zv = zin_d[(long)at * H4 + (long)g * 512 + cell];

        float acc = 0.f;
        if (t > 0) {
            int at_prev = (dir == 0) ? (t - 1) : (SEQ - t);
            const unsigned long long* src =
                (const unsigned long long*)(out + (long)at_prev * H2 + dir * HID) + l * 4;
            unsigned long long a0, a1, a2, a3;
            for (;;) {
                a0 = __hip_atomic_load(src + 0, __ATOMIC_RELAXED, __HIP_MEMORY_SCOPE_AGENT);
                a1 = __hip_atomic_load(src + 1, __ATOMIC_RELAXED, __HIP_MEMORY_SCOPE_AGENT);
                a2 = __hip_atomic_load(src + 2, __ATOMIC_RELAXED, __HIP_MEMORY_SCOPE_AGENT);
                a3 = __hip_atomic_load(src + 3, __ATOMIC_RELAXED, __HIP_MEMORY_SCOPE_AGENT);
                if (!(badw(a0) | badw(a1) | badw(a2) | badw(a3))) break;
                __builtin_amdgcn_s_sleep(1);
            }
            // lane covers h[8l .. 8l+8): chunk l>>4, in-chunk offset 8*(l&15)
            union { unsigned long long u; float2 f; } u0{a0}, u1{a1}, u2{a2}, u3{a3};
            float4 v0 = {u0.f.x, u0.f.y, u1.f.x, u1.f.y};
            float4 v1 = {u2.f.x, u2.f.y, u3.f.x, u3.f.y};
            float* dst = myLds + (l >> 4) * 132 + (l & 15) * 8;
            ((float4*)dst)[0] = v0;
            ((float4*)dst)[1] = v1;
            // MAC over own k quarter (16-lane broadcast groups, banks split
            // by the 132-stride pad -> conflict-free)
            const float4* hc = (const float4*)(myLds + kp * 132);
            #pragma unroll
            for (int j = 0; j < 32; j++) {
                float4 h = hc[j];
                acc += wreg[4*j+0] * h.x + wreg[4*j+1] * h.y
                     + wreg[4*j+2] * h.z + wreg[4*j+3] * h.w;
            }
        }
        // k-quarter reduction within the quad
        acc += __shfl_xor(acc, 1);
        acc += __shfl_xor(acc, 2);
        float zsum = acc + zv;             // full gate preact on kp==0 lanes
        // gate gather: actlane l reads f/g/o from lanes l+16 / l+32 / l+48
        float zf = __shfl(zsum, (l & 15) + 16);
        float zg = __shfl(zsum, (l & 15) + 32);
        float zo = __shfl(zsum, (l & 15) + 48);
        if (actlane) {
            float cc = sigmf(zf) * c_st + sigmf(zsum) * tanhf_fast(zg);
            c_st = cc;
            float hh = sigmf(zo) * tanhf_fast(cc);
            // single publish: the out-write IS the ready flag
            __hip_atomic_store(out + (long)at * H2 + dir * HID + cell, hh,
                               __ATOMIC_RELAXED, __HIP_MEMORY_SCOPE_AGENT);
        }
    }
}

// ---------------------------------------------------------------- avail build
__global__ __launch_bounds__(256)
void build_avail(const float* __restrict__ lstm_out, float* __restrict__ avail)
{
    long idx = (long)blockIdx.x * 256 + threadIdx.x;   // over MPAD*H2
    if (idx >= (long)MPAD * H2) return;
    int i = (int)(idx >> 10);
    int c = (int)(idx & 1023);
    float v = 0.f;
    if (i >= 1 && i <= SEQ) v = lstm_out[(long)(i - 1) * H2 + c];
    avail[idx] = v;
}

// ---------------------------------------------------------------- transpose
__global__ __launch_bounds__(256)
void transpose_w(const float* __restrict__ W, float* __restrict__ WT, int rows, int cols)
{
    int idx = blockIdx.x * 256 + threadIdx.x;
    if (idx >= rows * cols) return;
    int rr = idx / cols, cc = idx % cols;
    WT[cc * rows + rr] = W[idx];
}

// ---------------------------------------------------------------- pair MLP
#define STR1 257
#define STR2 129
__global__ __launch_bounds__(256)
void pair_kernel(const float* __restrict__ Abuf, const float* __restrict__ Bbuf,
                 const float* __restrict__ b1, const float* __restrict__ W2T,
                 const float* __restrict__ b2, const float* __restrict__ W3T,
                 const float* __restrict__ b3, const float* __restrict__ W4,
                 const float* __restrict__ b4, float* __restrict__ S)
{
    __shared__ float At[8 * STR1];
    __shared__ float Bt[8 * STR1];
    __shared__ float b1s[256];
    __shared__ float h2s[64 * STR2];
    __shared__ float spart[4 * 64];
    int tid = threadIdx.x;
    int i0 = blockIdx.y * 8, j0 = blockIdx.x * 8;
    {
        int rr = tid >> 5;
        int cbase = (tid & 31) * 8;
        #pragma unroll
        for (int u = 0; u < 8; u++) {
            At[rr * STR1 + cbase + u] = Abuf[(long)(i0 + rr) * 256 + cbase + u];
            Bt[rr * STR1 + cbase + u] = Bbuf[(long)(j0 + rr) * 256 + cbase + u];
        }
        b1s[tid] = b1[tid];
    }
    __syncthreads();
    int w = tid >> 6;
    int lane = tid & 63;          // pair id
    int ii = lane >> 3, jj = lane & 7;
    // phase 2: h1 (on the fly) -> h2
    #pragma unroll 1
    for (int blk = 0; blk < 4; blk++) {
        int c2b = __builtin_amdgcn_readfirstlane(w * 32 + blk * 8);
        float acc[8] = {};
        #pragma unroll 4
        for (int c1 = 0; c1 < 256; c1++) {
            float h1v = At[ii * STR1 + c1] + Bt[jj * STR1 + c1] + b1s[c1];
            h1v = fmaxf(h1v, 0.f);
            const float* wrow = W2T + c1 * 128 + c2b;
            #pragma unroll
            for (int u = 0; u < 8; u++) acc[u] += wrow[u] * h1v;
        }
        #pragma unroll
        for (int u = 0; u < 8; u++)
            h2s[lane * STR2 + c2b + u] = fmaxf(acc[u] + b2[c2b + u], 0.f);
    }
    __syncthreads();
    // phase 3: h2 -> h3, W4 fused
    float sp = 0.f;
    #pragma unroll 1
    for (int blk = 0; blk < 2; blk++) {
        int c3b = __builtin_amdgcn_readfirstlane(w * 16 + blk * 8);
        float acc[8] = {};
        #pragma unroll 4
        for (int c2 = 0; c2 < 128; c2++) {
            float h2v = h2s[lane * STR2 + c2];
            const float* wrow = W3T + c2 * 64 + c3b;
            #pragma unroll
            for (int u = 0; u < 8; u++) acc[u] += wrow[u] * h2v;
        }
        #pragma unroll
        for (int u = 0; u < 8; u++) {
            float v = fmaxf(acc[u] + b3[c3b + u], 0.f);
            sp += W4[c3b + u] * v;
        }
    }
    spart[w * 64 + lane] = sp;
    __syncthreads();
    if (tid < 64) {
        float s = spart[tid] + spart[64 + tid] + spart[128 + tid] + spart[192 + tid] + b4[0];
        int i = i0 + (tid >> 3), j = j0 + (tid & 7);
        if (i < NN && j < NN) S[(long)i * NN + j] = s;
    }
}

// ---------------------------------------------------------------- softmax+loss
__global__ __launch_bounds__(256)
void softmax_row(const float* __restrict__ S, const int* __restrict__ heads,
                 float* __restrict__ probs, float* __restrict__ rowloss)
{
    int i = blockIdx.x;
    int tid = threadIdx.x;
    __shared__ float red[256];
    __shared__ float srow[NN];
    const float* Si = S + (long)i * NN;
    float mx = -1e30f;
    for (int j = tid; j < NN; j += 256) { float v = Si[j]; srow[j] = v; mx = fmaxf(mx, v); }
    red[tid] = mx; __syncthreads();
    for (int s = 128; s > 0; s >>= 1) { if (tid < s) red[tid] = fmaxf(red[tid], red[tid + s]); __syncthreads(); }
    mx = red[0]; __syncthreads();
    float sum = 0.f, sq = 0.f;
    int hd = heads[i];
    for (int j = tid; j < NN; j += 256) {
        float v = srow[j];
        sum += __expf(v - mx);
        float t = (j == hd) ? 100.f : 0.f;
        float d = v - t; sq += d * d;
    }
    red[tid] = sum; __syncthreads();
    for (int s = 128; s > 0; s >>= 1) { if (tid < s) red[tid] += red[tid + s]; __syncthreads(); }
    sum = red[0]; __syncthreads();
    red[tid] = sq; __syncthreads();
    for (int s = 128; s > 0; s >>= 1) { if (tid < s) red[tid] += red[tid + s]; __syncthreads(); }
    if (tid == 0) rowloss[i] = red[0];
    float inv = 1.f / sum;
    for (int j = tid; j < NN; j += 256) probs[(long)i * NN + j] = __expf(srow[j] - mx) * inv;
}

__global__ __launch_bounds__(256)
void finish_loss(const float* __restrict__ rowloss, float* __restrict__ out0)
{
    __shared__ float red[256];
    int tid = threadIdx.x;
    float s = 0.f;
    for (int i = tid; i < NN; i += 256) s += rowloss[i];
    red[tid] = s; __syncthreads();
    for (int k = 128; k > 0; k >>= 1) { if (tid < k) red[tid] += red[tid + k]; __syncthreads(); }
    if (tid == 0) out0[0] = red[0] / ((float)NN * (float)NN);
}

// ---------------------------------------------------------------- launch
extern "C" void kernel_launch(void* const* d_in, const int* in_sizes, int n_in,
                              void* d_out, int out_size, void* d_ws, size_t ws_size,
                              hipStream_t stream)
{
    const float* x     = (const float*)d_in[0];
    const int*   heads = (const int*)  d_in[1];
    const float* Wih0  = (const float*)d_in[2];
    const float* Whh0  = (const float*)d_in[3];
    const float* b0    = (const float*)d_in[4];
    const float* Wih_r = (const float*)d_in[5];
    const float* Whh_r = (const float*)d_in[6];
    const float* b_r   = (const float*)d_in[7];
    const float* W1    = (const float*)d_in[8];
    const float* b1    = (const float*)d_in[9];
    const float* W2    = (const float*)d_in[10];
    const float* b2    = (const float*)d_in[11];
    const float* W3    = (const float*)d_in[12];
    const float* b3    = (const float*)d_in[13];
    const float* W4    = (const float*)d_in[14];
    const float* b4    = (const float*)d_in[15];
    float* out = (float*)d_out;

    char* ws = (char*)d_ws;
    // ws layout (bytes)
    const size_t o_zin  = 0;                       // 2*512*2048 f = 8 MB
    const size_t o_outA = o_zin  + (size_t)2 * SEQ * H4 * 4 + 512;
    const size_t o_outB = o_outA + (size_t)SEQ * H2 * 4 + 512;
    const size_t o_avail= o_outB + (size_t)SEQ * H2 * 4 + 512;
    const size_t o_Abuf = o_avail+ (size_t)MPAD * H2 * 4 + 512;
    const size_t o_Bbuf = o_Abuf + (size_t)MPAD * 256 * 4 + 512;
    const size_t o_W2T  = o_Bbuf + (size_t)MPAD * 256 * 4 + 512;
    const size_t o_W3T  = o_W2T  + 256 * 128 * 4 + 512;
    const size_t o_S    = o_W3T  + 128 * 64 * 4 + 512;
    const size_t o_rl   = o_S    + (size_t)NN * NN * 4 + 512;

    float* zin   = (float*)(ws + o_zin);
    float* outA  = (float*)(ws + o_outA);
    float* outB  = (float*)(ws + o_outB);
    float* avail = (float*)(ws + o_avail);
    float* Abuf  = (float*)(ws + o_Abuf);
    float* Bbuf  = (float*)(ws + o_Bbuf);
    float* W2T   = (float*)(ws + o_W2T);
    float* W3T   = (float*)(ws + o_W3T);
    float* Sbuf  = (float*)(ws + o_S);
    float* rowl  = (float*)(ws + o_rl);

    const size_t outBytes = (size_t)SEQ * H2 * 4;   // 2 MB

    // layer 0
    gemm_nt<<<dim3(H4 / 64, SEQ / 64, 2), 256, 0, stream>>>(
        x, EMB, 0, Wih0, EMB, (long)H4 * EMB, b0, H4,
        zin, H4, (long)SEQ * H4, EMB);
    hipMemsetAsync(outA, 0xFF, outBytes, stream);   // sentinel fill for poll
    lstm_layer<<<64, 256, 0, stream>>>(zin, Whh0, outA);

    // layers 1..3 (dst pre-filled 0xFF after its last reader finished)
    float* bufs[2] = { outA, outB };
    for (int l = 1; l <= 3; l++) {
        const float* src = bufs[(l - 1) & 1];
        float* dst = bufs[l & 1];
        gemm_nt<<<dim3(H4 / 64, SEQ / 64, 2), 256, 0, stream>>>(
            src, H2, 0, Wih_r + (size_t)(l - 1) * 2 * H4 * H2, H2, (long)H4 * H2,
            b_r + (size_t)(l - 1) * 2 * H4, H4,
            zin, H4, (long)SEQ * H4, H2);
        hipMemsetAsync(dst, 0xFF, outBytes, stream);
        lstm_layer<<<64, 256, 0, stream>>>(
            zin, Whh_r + (size_t)(l - 1) * 2 * H4 * HID, dst);
    }
    float* lstm_final = bufs[3 & 1];   // outB

    build_avail<<<(MPAD * H2) / 256, 256, 0, stream>>>(lstm_final, avail);

    // A = avail @ W1[:, :1024].T ; B = avail @ W1[:, 1024:].T
    gemm_nt<<<dim3(256 / 64, MPAD / 64, 1), 256, 0, stream>>>(
        avail, H2, 0, W1, 2048, 0, nullptr, 0, Abuf, 256, 0, H2);
    gemm_nt<<<dim3(256 / 64, MPAD / 64, 1), 256, 0, stream>>>(
        avail, H2, 0, W1 + 1024, 2048, 0, nullptr, 0, Bbuf, 256, 0, H2);

    transpose_w<<<(128 * 256) / 256, 256, 0, stream>>>(W2, W2T, 128, 256);
    transpose_w<<<(64 * 128) / 256, 256, 0, stream>>>(W3, W3T, 64, 128);

    pair_kernel<<<dim3(65, 65), 256, 0, stream>>>(
        Abuf, Bbuf, b1, W2T, b2, W3T, b3, W4, b4, Sbuf);

    softmax_row<<<NN, 256, 0, stream>>>(Sbuf, heads, out + 1, rowl);
    finish_loss<<<1, 256, 0, stream>>>(rowl, out);
}

// Round 6
// 5093.898 us; speedup vs baseline: 1.4974x; 1.4974x over previous
//
#include <hip/hip_runtime.h>
#include <math.h>

#define HID 512
#define SEQ 512
#define EMB 345
#define NN  513
#define MPAD 576
#define H4  2048
#define H2  1024

// ---------------------------------------------------------------- GEMM (NT)
// C[m][n] = sum_k A[m][k]*B[n][k] (+ bias[n]); BM=BN=64, TK=16, 256 thr, 4x4
__global__ __launch_bounds__(256)
void gemm_nt(const float* __restrict__ A, int lda, long aStride,
             const float* __restrict__ B, int ldb, long bStride,
             const float* __restrict__ bias, long biasStride,
             float* __restrict__ C, int ldc, long cStride, int K)
{
    int z = blockIdx.z;
    A += (long)z * aStride; B += (long)z * bStride; C += (long)z * cStride;
    const float* bptr = bias ? bias + (long)z * biasStride : nullptr;
    __shared__ float As[16][68];
    __shared__ float Bs[16][68];
    int tid = threadIdx.x;
    int tx = tid & 15, ty = tid >> 4;
    int m0 = blockIdx.y * 64, n0 = blockIdx.x * 64;
    float acc[4][4] = {};
    for (int k0 = 0; k0 < K; k0 += 16) {
        #pragma unroll
        for (int i = 0; i < 4; i++) {
            int id = tid + 256 * i;
            int mn = id >> 4, kk = id & 15;
            int k = k0 + kk;
            As[kk][mn] = (k < K) ? A[(long)(m0 + mn) * lda + k] : 0.f;
            Bs[kk][mn] = (k < K) ? B[(long)(n0 + mn) * ldb + k] : 0.f;
        }
        __syncthreads();
        #pragma unroll
        for (int kk = 0; kk < 16; kk++) {
            float a[4], b[4];
            #pragma unroll
            for (int i = 0; i < 4; i++) a[i] = As[kk][ty * 4 + i];
            #pragma unroll
            for (int j = 0; j < 4; j++) b[j] = Bs[kk][tx * 4 + j];
            #pragma unroll
            for (int i = 0; i < 4; i++)
                #pragma unroll
                for (int j = 0; j < 4; j++) acc[i][j] += a[i] * b[j];
        }
        __syncthreads();
    }
    #pragma unroll
    for (int i = 0; i < 4; i++) {
        int m = m0 + ty * 4 + i;
        #pragma unroll
        for (int j = 0; j < 4; j++) {
            int n = n0 + tx * 4 + j;
            float v = acc[i][j];
            if (bptr) v += bptr[n];
            C[(long)m * ldc + n] = v;
        }
    }
}

// ---------------------------------------------------------------- LSTM layer
// fast activations: v_exp_f32 + v_rcp_f32 (~1e-6 rel err; tolerance is 0.39)
__device__ __forceinline__ float sigmf(float x)
{ return __builtin_amdgcn_rcpf(1.f + __expf(-x)); }
__device__ __forceinline__ float tanhf_fast(float x)
{ return 1.f - 2.f * __builtin_amdgcn_rcpf(1.f + __expf(2.f * x)); }
// x=+inf: exp=inf, rcp=0 -> 1; x=-inf: exp=0 -> -1. No NaN.

__device__ __forceinline__ bool badw(unsigned long long a)
{ return ((unsigned)a == 0xFFFFFFFFu) || ((unsigned)(a >> 32) == 0xFFFFFFFFu); }

// 128 WGs: wg>>6 = dir, (wg&63)*8 = cell base (8 cells/WG).
// Lane map tid = ci*32 + g*8 + kp  (ci cell 0..7, g gate 0..3, kp k-eighth).
// Whh slice (32 rows x 512 = 64 KB) staged ONCE into LDS in column layout
// w_lds[j][tid] — each thread reads only its own column (bank = tid%32,
// 2-way = free; no barrier needed: producer==consumer). Per step the 64
// w-reads are pre-issued BEFORE the poll so the LDS stream hides under the
// poll latency. h staged cooperatively (1 ull/thread, data-as-flag 0xFF
// sentinel) into padded chunks (stride 68 -> conflict-free b128), double-
// buffered, ONE barrier/step. k-reduce 3 shfl_xor; gate gather 3 shfl —
// everything intra-wave. Activation+publish on lanes tid%32==0.
__global__ __launch_bounds__(256, 1)
void lstm_layer(const float* __restrict__ zin,   // [2][SEQ][H4]
                const float* __restrict__ Whh,   // [2][H4][HID]
                float* out)                      // [SEQ][H2], pre-memset 0xFF
{
    int wg  = blockIdx.x;
    int dir = wg >> 6;
    int cb  = (wg & 63) * 8;
    int tid = threadIdx.x;
    int ci  = tid >> 5;          // cell in group 0..7
    int g   = (tid >> 3) & 3;    // gate (torch order i,f,g,o)
    int kp  = tid & 7;           // k-eighth
    int cell = cb + ci;
    long row = (long)g * 512 + cell;

    __shared__ float w_lds[64 * 256];    // [j][tid], 64 KB
    __shared__ float h_st[2][8 * 68];    // double-buffered h, padded chunks

    // one-time weight staging: thread's own 64 weights -> own LDS column
    {
        const float4* wp = (const float4*)(Whh + ((long)dir * H4 + row) * HID + kp * 64);
        #pragma unroll
        for (int j4 = 0; j4 < 16; j4++) {
            float4 w = wp[j4];
            w_lds[(4 * j4 + 0) * 256 + tid] = w.x;
            w_lds[(4 * j4 + 1) * 256 + tid] = w.y;
            w_lds[(4 * j4 + 2) * 256 + tid] = w.z;
            w_lds[(4 * j4 + 3) * 256 + tid] = w.w;
        }
    }

    const float* zin_d = zin + (long)dir * SEQ * H4;
    float c_st = 0.f;
    bool actlane = ((tid & 31) == 0);
    int hc = tid >> 5;           // staging chunk = high bits of element pair
    int ho = 2 * (tid & 31);     // offset within chunk

    for (int t = 0; t < SEQ; t++) {
        int at = (dir == 0) ? t : (SEQ - 1 - t);
        // pre-issue weight reads (complete during the poll)
        float wv[64];
        #pragma unroll
        for (int j = 0; j < 64; j++) wv[j] = w_lds[j * 256 + tid];
        // zin prefetch (kp==0 lanes only need it)
        float zv = 0.f;
        if (kp == 0) zv = zin_d[(long)at * H4 + (long)g * 512 + cell];

        if (t == 0) {
            *(float2*)&h_st[0][hc * 68 + ho] = make_float2(0.f, 0.f);
        } else {
            int at_prev = (dir == 0) ? (t - 1) : (SEQ - t);
            const unsigned long long* src =
                (const unsigned long long*)(out + (long)at_prev * H2 + dir * HID) + tid;
            unsigned long long a = __hip_atomic_load(src, __ATOMIC_RELAXED, __HIP_MEMORY_SCOPE_AGENT);
            while (badw(a)) {
                __builtin_amdgcn_s_sleep(1);
                a = __hip_atomic_load(src, __ATOMIC_RELAXED, __HIP_MEMORY_SCOPE_AGENT);
            }
            union { unsigned long long u; float2 f; } cv; cv.u = a;
            *(float2*)&h_st[t & 1][hc * 68 + ho] = cv.f;
        }
        __syncthreads();       // the ONLY barrier per step (dbuf protects reuse)

        // MAC over own k-eighth: h chunk kp, broadcast within kp-group
        const float4* hp = (const float4*)&h_st[t & 1][kp * 68];
        float acc = 0.f;
        #pragma unroll
        for (int j4 = 0; j4 < 16; j4++) {
            float4 h = hp[j4];
            acc += wv[4*j4+0] * h.x + wv[4*j4+1] * h.y
                 + wv[4*j4+2] * h.z + wv[4*j4+3] * h.w;
        }
        // k-reduce within the 8-lane group
        acc += __shfl_xor(acc, 1);
        acc += __shfl_xor(acc, 2);
        acc += __shfl_xor(acc, 4);
        float zsum = acc + zv;             // full gate preact on kp==0 lanes
        // gate gather (intra-wave): act lane l&32 reads lanes +8/+16/+24
        float zf = __shfl(zsum, (tid & 32) + 8);
        float zg = __shfl(zsum, (tid & 32) + 16);
        float zo = __shfl(zsum, (tid & 32) + 24);
        if (actlane) {
            float cc = sigmf(zf) * c_st + sigmf(zsum) * tanhf_fast(zg);
            c_st = cc;
            float hh = sigmf(zo) * tanhf_fast(cc);
            // single publish: the out-write IS the ready flag
            __hip_atomic_store(out + (long)at * H2 + dir * HID + cell, hh,
                               __ATOMIC_RELAXED, __HIP_MEMORY_SCOPE_AGENT);
        }
    }
}

// ---------------------------------------------------------------- avail build
__global__ __launch_bounds__(256)
void build_avail(const float* __restrict__ lstm_out, float* __restrict__ avail)
{
    long idx = (long)blockIdx.x * 256 + threadIdx.x;   // over MPAD*H2
    if (idx >= (long)MPAD * H2) return;
    int i = (int)(idx >> 10);
    int c = (int)(idx & 1023);
    float v = 0.f;
    if (i >= 1 && i <= SEQ) v = lstm_out[(long)(i - 1) * H2 + c];
    avail[idx] = v;
}

// ---------------------------------------------------------------- transpose
__global__ __launch_bounds__(256)
void transpose_w(const float* __restrict__ W, float* __restrict__ WT, int rows, int cols)
{
    int idx = blockIdx.x * 256 + threadIdx.x;
    if (idx >= rows * cols) return;
    int rr = idx / cols, cc = idx % cols;
    WT[cc * rows + rr] = W[idx];
}

// ---------------------------------------------------------------- pair MLP
#define STR1 257
#define STR2 129
__global__ __launch_bounds__(256)
void pair_kernel(const float* __restrict__ Abuf, const float* __restrict__ Bbuf,
                 const float* __restrict__ b1, const float* __restrict__ W2T,
                 const float* __restrict__ b2, const float* __restrict__ W3T,
                 const float* __restrict__ b3, const float* __restrict__ W4,
                 const float* __restrict__ b4, float* __restrict__ S)
{
    __shared__ float At[8 * STR1];
    __shared__ float Bt[8 * STR1];
    __shared__ float b1s[256];
    __shared__ float h2s[64 * STR2];
    __shared__ float spart[4 * 64];
    int tid = threadIdx.x;
    int i0 = blockIdx.y * 8, j0 = blockIdx.x * 8;
    {
        int rr = tid >> 5;
        int cbase = (tid & 31) * 8;
        #pragma unroll
        for (int u = 0; u < 8; u++) {
            At[rr * STR1 + cbase + u] = Abuf[(long)(i0 + rr) * 256 + cbase + u];
            Bt[rr * STR1 + cbase + u] = Bbuf[(long)(j0 + rr) * 256 + cbase + u];
        }
        b1s[tid] = b1[tid];
    }
    __syncthreads();
    int w = tid >> 6;
    int lane = tid & 63;          // pair id
    int ii = lane >> 3, jj = lane & 7;
    // phase 2: h1 (on the fly) -> h2
    #pragma unroll 1
    for (int blk = 0; blk < 4; blk++) {
        int c2b = __builtin_amdgcn_readfirstlane(w * 32 + blk * 8);
        float acc[8] = {};
        #pragma unroll 4
        for (int c1 = 0; c1 < 256; c1++) {
            float h1v = At[ii * STR1 + c1] + Bt[jj * STR1 + c1] + b1s[c1];
            h1v = fmaxf(h1v, 0.f);
            const float* wrow = W2T + c1 * 128 + c2b;
            #pragma unroll
            for (int u = 0; u < 8; u++) acc[u] += wrow[u] * h1v;
        }
        #pragma unroll
        for (int u = 0; u < 8; u++)
            h2s[lane * STR2 + c2b + u] = fmaxf(acc[u] + b2[c2b + u], 0.f);
    }
    __syncthreads();
    // phase 3: h2 -> h3, W4 fused
    float sp = 0.f;
    #pragma unroll 1
    for (int blk = 0; blk < 2; blk++) {
        int c3b = __builtin_amdgcn_readfirstlane(w * 16 + blk * 8);
        float acc[8] = {};
        #pragma unroll 4
        for (int c2 = 0; c2 < 128; c2++) {
            float h2v = h2s[lane * STR2 + c2];
            const float* wrow = W3T + c2 * 64 + c3b;
            #pragma unroll
            for (int u = 0; u < 8; u++) acc[u] += wrow[u] * h2v;
        }
        #pragma unroll
        for (int u = 0; u < 8; u++) {
            float v = fmaxf(acc[u] + b3[c3b + u], 0.f);
            sp += W4[c3b + u] * v;
        }
    }
    spart[w * 64 + lane] = sp;
    __syncthreads();
    if (tid < 64) {
        float s = spart[tid] + spart[64 + tid] + spart[128 + tid] + spart[192 + tid] + b4[0];
        int i = i0 + (tid >> 3), j = j0 + (tid & 7);
        if (i < NN && j < NN) S[(long)i * NN + j] = s;
    }
}

// ---------------------------------------------------------------- softmax+loss
__global__ __launch_bounds__(256)
void softmax_row(const float* __restrict__ S, const int* __restrict__ heads,
                 float* __restrict__ probs, float* __restrict__ rowloss)
{
    int i = blockIdx.x;
    int tid = threadIdx.x;
    __shared__ float red[256];
    __shared__ float srow[NN];
    const float* Si = S + (long)i * NN;
    float mx = -1e30f;
    for (int j = tid; j < NN; j += 256) { float v = Si[j]; srow[j] = v; mx = fmaxf(mx, v); }
    red[tid] = mx; __syncthreads();
    for (int s = 128; s > 0; s >>= 1) { if (tid < s) red[tid] = fmaxf(red[tid], red[tid + s]); __syncthreads(); }
    mx = red[0]; __syncthreads();
    float sum = 0.f, sq = 0.f;
    int hd = heads[i];
    for (int j = tid; j < NN; j += 256) {
        float v = srow[j];
        sum += __expf(v - mx);
        float t = (j == hd) ? 100.f : 0.f;
        float d = v - t; sq += d * d;
    }
    red[tid] = sum; __syncthreads();
    for (int s = 128; s > 0; s >>= 1) { if (tid < s) red[tid] += red[tid + s]; __syncthreads(); }
    sum = red[0]; __syncthreads();
    red[tid] = sq; __syncthreads();
    for (int s = 128; s > 0; s >>= 1) { if (tid < s) red[tid] += red[tid + s]; __syncthreads(); }
    if (tid == 0) rowloss[i] = red[0];
    float inv = 1.f / sum;
    for (int j = tid; j < NN; j += 256) probs[(long)i * NN + j] = __expf(srow[j] - mx) * inv;
}

__global__ __launch_bounds__(256)
void finish_loss(const float* __restrict__ rowloss, float* __restrict__ out0)
{
    __shared__ float red[256];
    int tid = threadIdx.x;
    float s = 0.f;
    for (int i = tid; i < NN; i += 256) s += rowloss[i];
    red[tid] = s; __syncthreads();
    for (int k = 128; k > 0; k >>= 1) { if (tid < k) red[tid] += red[tid + k]; __syncthreads(); }
    if (tid == 0) out0[0] = red[0] / ((float)NN * (float)NN);
}

// ---------------------------------------------------------------- launch
extern "C" void kernel_launch(void* const* d_in, const int* in_sizes, int n_in,
                              void* d_out, int out_size, void* d_ws, size_t ws_size,
                              hipStream_t stream)
{
    const float* x     = (const float*)d_in[0];
    const int*   heads = (const int*)  d_in[1];
    const float* Wih0  = (const float*)d_in[2];
    const float* Whh0  = (const float*)d_in[3];
    const float* b0    = (const float*)d_in[4];
    const float* Wih_r = (const float*)d_in[5];
    const float* Whh_r = (const float*)d_in[6];
    const float* b_r   = (const float*)d_in[7];
    const float* W1    = (const float*)d_in[8];
    const float* b1    = (const float*)d_in[9];
    const float* W2    = (const float*)d_in[10];
    const float* b2    = (const float*)d_in[11];
    const float* W3    = (const float*)d_in[12];
    const float* b3    = (const float*)d_in[13];
    const float* W4    = (const float*)d_in[14];
    const float* b4    = (const float*)d_in[15];
    float* out = (float*)d_out;

    char* ws = (char*)d_ws;
    // ws layout (bytes)
    const size_t o_zin  = 0;                       // 2*512*2048 f = 8 MB
    const size_t o_outA = o_zin  + (size_t)2 * SEQ * H4 * 4 + 512;
    const size_t o_outB = o_outA + (size_t)SEQ * H2 * 4 + 512;
    const size_t o_avail= o_outB + (size_t)SEQ * H2 * 4 + 512;
    const size_t o_Abuf = o_avail+ (size_t)MPAD * H2 * 4 + 512;
    const size_t o_Bbuf = o_Abuf + (size_t)MPAD * 256 * 4 + 512;
    const size_t o_W2T  = o_Bbuf + (size_t)MPAD * 256 * 4 + 512;
    const size_t o_W3T  = o_W2T  + 256 * 128 * 4 + 512;
    const size_t o_S    = o_W3T  + 128 * 64 * 4 + 512;
    const size_t o_rl   = o_S    + (size_t)NN * NN * 4 + 512;

    float* zin   = (float*)(ws + o_zin);
    float* outA  = (float*)(ws + o_outA);
    float* outB  = (float*)(ws + o_outB);
    float* avail = (float*)(ws + o_avail);
    float* Abuf  = (float*)(ws + o_Abuf);
    float* Bbuf  = (float*)(ws + o_Bbuf);
    float* W2T   = (float*)(ws + o_W2T);
    float* W3T   = (float*)(ws + o_W3T);
    float* Sbuf  = (float*)(ws + o_S);
    float* rowl  = (float*)(ws + o_rl);

    const size_t outBytes = (size_t)SEQ * H2 * 4;   // 2 MB

    // layer 0
    gemm_nt<<<dim3(H4 / 64, SEQ / 64, 2), 256, 0, stream>>>(
        x, EMB, 0, Wih0, EMB, (long)H4 * EMB, b0, H4,
        zin, H4, (long)SEQ * H4, EMB);
    hipMemsetAsync(outA, 0xFF, outBytes, stream);   // sentinel fill for poll
    lstm_layer<<<128, 256, 0, stream>>>(zin, Whh0, outA);

    // layers 1..3 (dst pre-filled 0xFF after its last reader finished)
    float* bufs[2] = { outA, outB };
    for (int l = 1; l <= 3; l++) {
        const float* src = bufs[(l - 1) & 1];
        float* dst = bufs[l & 1];
        gemm_nt<<<dim3(H4 / 64, SEQ / 64, 2), 256, 0, stream>>>(
            src, H2, 0, Wih_r + (size_t)(l - 1) * 2 * H4 * H2, H2, (long)H4 * H2,
            b_r + (size_t)(l - 1) * 2 * H4, H4,
            zin, H4, (long)SEQ * H4, H2);
        hipMemsetAsync(dst, 0xFF, outBytes, stream);
        lstm_layer<<<128, 256, 0, stream>>>(
            zin, Whh_r + (size_t)(l - 1) * 2 * H4 * HID, dst);
    }
    float* lstm_final = bufs[3 & 1];   // outB

    build_avail<<<(MPAD * H2) / 256, 256, 0, stream>>>(lstm_final, avail);

    // A = avail @ W1[:, :1024].T ; B = avail @ W1[:, 1024:].T
    gemm_nt<<<dim3(256 / 64, MPAD / 64, 1), 256, 0, stream>>>(
        avail, H2, 0, W1, 2048, 0, nullptr, 0, Abuf, 256, 0, H2);
    gemm_nt<<<dim3(256 / 64, MPAD / 64, 1), 256, 0, stream>>>(
        avail, H2, 0, W1 + 1024, 2048, 0, nullptr, 0, Bbuf, 256, 0, H2);

    transpose_w<<<(128 * 256) / 256, 256, 0, stream>>>(W2, W2T, 128, 256);
    transpose_w<<<(64 * 128) / 256, 256, 0, stream>>>(W3, W3T, 64, 128);

    pair_kernel<<<dim3(65, 65), 256, 0, stream>>>(
        Abuf, Bbuf, b1, W2T, b2, W3T, b3, W4, b4, Sbuf);

    softmax_row<<<NN, 256, 0, stream>>>(Sbuf, heads, out + 1, rowl);
    finish_loss<<<1, 256, 0, stream>>>(rowl, out);
}